// Round 1
// 829.555 us; speedup vs baseline: 2.8517x; 2.8517x over previous
//
#include <hip/hip_runtime.h>
#include <stdint.h>

#define HMAP_MASK ((1u << 19) - 1u)

// Locality-scheduled version: blockIdx.y selects a group of 8 consecutive
// subs (= one table, 8 levels, <=32 MB of table data); blockIdx.x (fastest-
// varying in dispatch order) selects a 32-point chunk. All concurrently
// resident blocks therefore hammer the SAME <=32 MB table window, which is
// L3-resident, instead of scattering across the full 244 MB -> HBM random-
// line thrash. Lanes si=0..7 within a wave write subs 8k..8k+7 of one point:
// each 64 B output line is fully written by one wave (coalesced, no
// amplification), so no transpose pass is needed.
__global__ __launch_bounds__(256) void energy4d_kernel(
    const float4* __restrict__ coords,
    const float4* __restrict__ refc,
    const float2* __restrict__ t0,
    const float2* __restrict__ t1,
    const float2* __restrict__ t2,
    const float2* __restrict__ t3,
    float2* __restrict__ out, int npts)
{
    // Match XLA-f32 semantics bit-for-bit: no fma contraction anywhere in the
    // u/pos/w chain (XLA rounds each HLO op separately).
    #pragma clang fp contract(off)

    int t = threadIdx.x;
    int si = t & 7;                 // slice within the 8-sub group
    int pi = t >> 3;                // 32 points per block
    int point = blockIdx.x * 32 + pi;
    if (point >= npts) return;
    int sub = (blockIdx.y << 3) + si;   // blockIdx.y = sub-group 0..7
    int table_id = sub >> 4;            // wave-uniform (group within one table)
    int level = sub & 15;

    float4 c = coords[point];
    float4 r = refc[point];
    float rx = c.x - r.x, ry = c.y - r.y, rz = c.z - r.z, rt = c.w - r.w;

    // _norm: XLA rewrites (v-lo)/(hi-lo) into (v-lo) * (1/(hi-lo)) with the
    // f32-rounded reciprocal (div-by-const -> recip-mul canonicalization).
    const float R180   = 1.0f / 180.0f;
    const float R360   = 1.0f / 360.0f;
    const float R20000 = 1.0f / 20000.0f;
    float x = fminf(fmaxf((rx + 90.0f)    * R180,   0.0f), 1.0f);
    float y = fminf(fmaxf((ry + 180.0f)   * R360,   0.0f), 1.0f);
    float z = fminf(fmaxf((rz + 11000.0f) * R20000, 0.0f), 1.0f);
    float tt = fminf(fmaxf(rt, 0.0f), 1.0f);          // /1.0 folds away
    float ts = (tt * 2.0f - 1.0f) * 0.9f;

    // dim selection per table: t0=(x,y,z) t1=(x,y,ts) t2=(y,z,ts) t3=(x,z,ts)
    float d0 = (table_id == 2) ? y : x;
    float d1 = (table_id <= 1) ? y : z;
    float d2 = (table_id == 0) ? z : ts;
    const float2* tab = (table_id == 0) ? t0
                      : (table_id == 1) ? t1
                      : (table_id == 2) ? t2 : t3;

    // hash_encode: u = clip((d+1)/2, 0, 1); /2 is exact as *0.5
    float u0 = fminf(fmaxf((d0 + 1.0f) * 0.5f, 0.0f), 1.0f);
    float u1 = fminf(fmaxf((d1 + 1.0f) * 0.5f, 0.0f), 1.0f);
    float u2 = fminf(fmaxf((d2 + 1.0f) * 0.5f, 0.0f), 1.0f);

    int res = 32 << level;                 // ceil(32*2^l) exact
    float resm1 = (float)(res - 1);
    float pos0 = u0 * resm1;
    float pos1 = u1 * resm1;
    float pos2 = u2 * resm1;
    int p0 = min(max((int)floorf(pos0), 0), res - 2);
    int p1 = min(max((int)floorf(pos1), 0), res - 2);
    int p2 = min(max((int)floorf(pos2), 0), res - 2);
    float w0 = pos0 - (float)p0;   // contract(off): uses rounded pos
    float w1 = pos1 - (float)p1;
    float w2 = pos2 - (float)p2;

    // level offsets: l0->0 (dense 32^3), l1->32768 (dense 64^3=262144),
    // l>=2 -> 294912 + (l-2)*524288 (hashed)
    int off = (level >= 2) ? (294912 + ((level - 2) << 19)) : (level << 15);
    bool use_hash = (level >= 2);
    const float2* tabo = tab + off;

    float om0 = 1.0f - w0, om1 = 1.0f - w1, om2 = 1.0f - w2;
    float a0 = 0.0f, a1 = 0.0f;
    uint32_t ures = (uint32_t)res;

    #pragma unroll
    for (int ci = 0; ci < 8; ++ci) {
        int cx = ci & 1, cy = (ci >> 1) & 1, cz = (ci >> 2) & 1;
        uint32_t px = (uint32_t)(p0 + cx);
        uint32_t py = (uint32_t)(p1 + cy);
        uint32_t pz = (uint32_t)(p2 + cz);
        uint32_t idx;
        if (use_hash) {
            idx = (px ^ (py * 2654435761u) ^ (pz * 805459861u)) & HMAP_MASK;
        } else {
            idx = px + ures * (py + ures * pz);
        }
        float2 f = tabo[idx];
        float ww = (cx ? w0 : om0) * (cy ? w1 : om1) * (cz ? w2 : om2);
        a0 += f.x * ww;
        a1 += f.y * ww;
    }

    // Nontemporal 8 B store: output is write-once streaming; keep it out of
    // L2/L3 so the table working set stays resident.
    float2 val = make_float2(a0, a1);
    unsigned long long bits;
    __builtin_memcpy(&bits, &val, 8);
    __builtin_nontemporal_store(bits,
        (unsigned long long*)(out + (size_t)point * 64 + sub));
}

extern "C" void kernel_launch(void* const* d_in, const int* in_sizes, int n_in,
                              void* d_out, int out_size, void* d_ws, size_t ws_size,
                              hipStream_t stream) {
    const float4* coords = (const float4*)d_in[0];
    const float4* refc   = (const float4*)d_in[1];
    const float2* t0 = (const float2*)d_in[2];
    const float2* t1 = (const float2*)d_in[3];
    const float2* t2 = (const float2*)d_in[4];
    const float2* t3 = (const float2*)d_in[5];
    float2* out = (float2*)d_out;
    int npts = in_sizes[0] / 4;
    int grid_x = (npts + 31) / 32;   // 32 points per block
    dim3 grid(grid_x, 8);            // y = sub-group (8 subs each)
    energy4d_kernel<<<grid, 256, 0, stream>>>(coords, refc, t0, t1, t2, t3, out, npts);
}

// Round 2
// 738.668 us; speedup vs baseline: 3.2026x; 1.1230x over previous
//
#include <hip/hip_runtime.h>
#include <stdint.h>

#define HMAP_MASK ((1u << 19) - 1u)

// ============================================================================
// 3-kernel XCD-partitioned design.
//
// R1 analysis: FETCH_SIZE (1.73 GB) == per-group working set (26 MB) x 8 XCDs
// x 8 groups, i.e. the kernel is bound by replicated L3->L2 fills of random
// 64 B lines at ~3 TB/s. Fix: partition the 64 (table,level) slices across
// XCDs via the round-robin blockIdx%8 -> XCD mapping. Each XCD then works one
// <=4 MB slice at a time -- exactly its private L2 capacity -- so every table
// line is filled into exactly ONE L2, once. Table fill: 1.7 GB -> 244 MB.
//
// kernel 1: normalize coords -> u (float4 x,y,z,ts), read per-phase (4 MB).
// kernel 2: gather; block bid -> xcd=bid&7, phase=j/chunks; slice=phase*8+xcd.
//           Writes slice-major stage[slice][point] (coalesced, nontemporal),
//           because direct out[point*64+sub] stores would be 8 B-scattered
//           with cross-XCD false sharing per 64 B line.
// kernel 3: LDS-tile transpose stage[sub][point] -> out[point][sub].
// ============================================================================

__global__ __launch_bounds__(256) void u_precompute_kernel(
    const float4* __restrict__ coords,
    const float4* __restrict__ refc,
    float4* __restrict__ uout, int npts)
{
    #pragma clang fp contract(off)
    int p = blockIdx.x * 256 + threadIdx.x;
    if (p >= npts) return;
    float4 c = coords[p];
    float4 r = refc[p];
    float rx = c.x - r.x, ry = c.y - r.y, rz = c.z - r.z, rt = c.w - r.w;
    const float R180   = 1.0f / 180.0f;    // XLA div->recip-mul canonicalization
    const float R360   = 1.0f / 360.0f;
    const float R20000 = 1.0f / 20000.0f;
    float x = fminf(fmaxf((rx + 90.0f)    * R180,   0.0f), 1.0f);
    float y = fminf(fmaxf((ry + 180.0f)   * R360,   0.0f), 1.0f);
    float z = fminf(fmaxf((rz + 11000.0f) * R20000, 0.0f), 1.0f);
    float tt = fminf(fmaxf(rt, 0.0f), 1.0f);
    float ts = (tt * 2.0f - 1.0f) * 0.9f;
    uout[p] = make_float4(x, y, z, ts);
}

__global__ __launch_bounds__(256) void gather_kernel(
    const float4* __restrict__ u,
    const float2* __restrict__ t0,
    const float2* __restrict__ t1,
    const float2* __restrict__ t2,
    const float2* __restrict__ t3,
    float2* __restrict__ stage, int npts, int chunks)
{
    #pragma clang fp contract(off)
    int bid = blockIdx.x;
    int xcd   = bid & 7;            // empirically: XCD id (round-robin dispatch)
    int j     = bid >> 3;           // per-XCD sequential index
    int phase = j / chunks;         // 0..7: which of this XCD's 8 slices
    int chunk = j - phase * chunks;
    int slice = phase * 8 + xcd;    // 0..63 = (table,level), one per XCD-phase
    int table_id = slice >> 4;      // all wave-uniform -> SALU
    int level    = slice & 15;

    int point = chunk * 256 + threadIdx.x;
    if (point >= npts) return;

    float4 uu = u[point];
    // dim selection per table: t0=(x,y,z) t1=(x,y,ts) t2=(y,z,ts) t3=(x,z,ts)
    float d0 = (table_id == 2) ? uu.y : uu.x;
    float d1 = (table_id <= 1) ? uu.y : uu.z;
    float d2 = (table_id == 0) ? uu.z : uu.w;
    const float2* tab = (table_id == 0) ? t0
                      : (table_id == 1) ? t1
                      : (table_id == 2) ? t2 : t3;

    // hash_encode: u = clip((d+1)/2, 0, 1); /2 exact as *0.5
    float u0 = fminf(fmaxf((d0 + 1.0f) * 0.5f, 0.0f), 1.0f);
    float u1 = fminf(fmaxf((d1 + 1.0f) * 0.5f, 0.0f), 1.0f);
    float u2 = fminf(fmaxf((d2 + 1.0f) * 0.5f, 0.0f), 1.0f);

    int res = 32 << level;                 // ceil(32*2^l) exact
    float resm1 = (float)(res - 1);
    float pos0 = u0 * resm1;
    float pos1 = u1 * resm1;
    float pos2 = u2 * resm1;
    int p0 = min(max((int)floorf(pos0), 0), res - 2);
    int p1 = min(max((int)floorf(pos1), 0), res - 2);
    int p2 = min(max((int)floorf(pos2), 0), res - 2);
    float w0 = pos0 - (float)p0;   // contract(off): uses rounded pos
    float w1 = pos1 - (float)p1;
    float w2 = pos2 - (float)p2;

    // level offsets: l0->0 (dense 32^3), l1->32768 (dense 64^3),
    // l>=2 -> 294912 + (l-2)*524288 (hashed)
    int off = (level >= 2) ? (294912 + ((level - 2) << 19)) : (level << 15);
    bool use_hash = (level >= 2);
    const float2* tabo = tab + off;

    float om0 = 1.0f - w0, om1 = 1.0f - w1, om2 = 1.0f - w2;
    float a0 = 0.0f, a1 = 0.0f;
    uint32_t ures = (uint32_t)res;

    #pragma unroll
    for (int ci = 0; ci < 8; ++ci) {
        int cx = ci & 1, cy = (ci >> 1) & 1, cz = (ci >> 2) & 1;
        uint32_t px = (uint32_t)(p0 + cx);
        uint32_t py = (uint32_t)(p1 + cy);
        uint32_t pz = (uint32_t)(p2 + cz);
        uint32_t idx;
        if (use_hash) {
            idx = (px ^ (py * 2654435761u) ^ (pz * 805459861u)) & HMAP_MASK;
        } else {
            idx = px + ures * (py + ures * pz);
        }
        float2 f = tabo[idx];
        float ww = (cx ? w0 : om0) * (cy ? w1 : om1) * (cz ? w2 : om2);
        a0 += f.x * ww;
        a1 += f.y * ww;
    }

    // slice-major staging: lanes write consecutive points -> 512 B contiguous
    // per wave. Nontemporal: write-once stream, keep table lines in L2.
    float2 val = make_float2(a0, a1);
    unsigned long long bits;
    __builtin_memcpy(&bits, &val, 8);
    __builtin_nontemporal_store(bits,
        (unsigned long long*)(stage + (size_t)slice * npts + point));
}

__global__ __launch_bounds__(256) void transpose_kernel(
    const float2* __restrict__ stage,
    float2* __restrict__ out, int npts)
{
    __shared__ float2 tile[64][65];   // +1 pad: column reads ~4-way, ok
    int pbase = blockIdx.x * 64;
    int lane = threadIdx.x & 63;
    int row4 = threadIdx.x >> 6;      // 0..3

    #pragma unroll
    for (int s = 0; s < 64; s += 4) {
        int sub = s + row4;
        int p = pbase + lane;
        if (p < npts)
            tile[sub][lane] = stage[(size_t)sub * npts + p];
    }
    __syncthreads();
    #pragma unroll
    for (int p4 = 0; p4 < 64; p4 += 4) {
        int p = pbase + p4 + row4;
        if (p < npts) {
            float2 v = tile[lane][p4 + row4];
            unsigned long long bits;
            __builtin_memcpy(&bits, &v, 8);
            __builtin_nontemporal_store(bits,
                (unsigned long long*)(out + (size_t)p * 64 + lane));
        }
    }
}

// ---------------- fallback (round-1 kernel) if workspace is too small -------
__global__ __launch_bounds__(256) void energy4d_fallback(
    const float4* __restrict__ coords,
    const float4* __restrict__ refc,
    const float2* __restrict__ t0,
    const float2* __restrict__ t1,
    const float2* __restrict__ t2,
    const float2* __restrict__ t3,
    float2* __restrict__ out, int npts)
{
    #pragma clang fp contract(off)
    int t = threadIdx.x;
    int si = t & 7;
    int pi = t >> 3;
    int point = blockIdx.x * 32 + pi;
    if (point >= npts) return;
    int sub = (blockIdx.y << 3) + si;
    int table_id = sub >> 4;
    int level = sub & 15;

    float4 c = coords[point];
    float4 r = refc[point];
    float rx = c.x - r.x, ry = c.y - r.y, rz = c.z - r.z, rt = c.w - r.w;
    const float R180   = 1.0f / 180.0f;
    const float R360   = 1.0f / 360.0f;
    const float R20000 = 1.0f / 20000.0f;
    float x = fminf(fmaxf((rx + 90.0f)    * R180,   0.0f), 1.0f);
    float y = fminf(fmaxf((ry + 180.0f)   * R360,   0.0f), 1.0f);
    float z = fminf(fmaxf((rz + 11000.0f) * R20000, 0.0f), 1.0f);
    float tt = fminf(fmaxf(rt, 0.0f), 1.0f);
    float ts = (tt * 2.0f - 1.0f) * 0.9f;

    float d0 = (table_id == 2) ? y : x;
    float d1 = (table_id <= 1) ? y : z;
    float d2 = (table_id == 0) ? z : ts;
    const float2* tab = (table_id == 0) ? t0
                      : (table_id == 1) ? t1
                      : (table_id == 2) ? t2 : t3;

    float u0 = fminf(fmaxf((d0 + 1.0f) * 0.5f, 0.0f), 1.0f);
    float u1 = fminf(fmaxf((d1 + 1.0f) * 0.5f, 0.0f), 1.0f);
    float u2 = fminf(fmaxf((d2 + 1.0f) * 0.5f, 0.0f), 1.0f);

    int res = 32 << level;
    float resm1 = (float)(res - 1);
    float pos0 = u0 * resm1;
    float pos1 = u1 * resm1;
    float pos2 = u2 * resm1;
    int p0 = min(max((int)floorf(pos0), 0), res - 2);
    int p1 = min(max((int)floorf(pos1), 0), res - 2);
    int p2 = min(max((int)floorf(pos2), 0), res - 2);
    float w0 = pos0 - (float)p0;
    float w1 = pos1 - (float)p1;
    float w2 = pos2 - (float)p2;

    int off = (level >= 2) ? (294912 + ((level - 2) << 19)) : (level << 15);
    bool use_hash = (level >= 2);
    const float2* tabo = tab + off;

    float om0 = 1.0f - w0, om1 = 1.0f - w1, om2 = 1.0f - w2;
    float a0 = 0.0f, a1 = 0.0f;
    uint32_t ures = (uint32_t)res;

    #pragma unroll
    for (int ci = 0; ci < 8; ++ci) {
        int cx = ci & 1, cy = (ci >> 1) & 1, cz = (ci >> 2) & 1;
        uint32_t px = (uint32_t)(p0 + cx);
        uint32_t py = (uint32_t)(p1 + cy);
        uint32_t pz = (uint32_t)(p2 + cz);
        uint32_t idx;
        if (use_hash) {
            idx = (px ^ (py * 2654435761u) ^ (pz * 805459861u)) & HMAP_MASK;
        } else {
            idx = px + ures * (py + ures * pz);
        }
        float2 f = tabo[idx];
        float ww = (cx ? w0 : om0) * (cy ? w1 : om1) * (cz ? w2 : om2);
        a0 += f.x * ww;
        a1 += f.y * ww;
    }

    float2 val = make_float2(a0, a1);
    unsigned long long bits;
    __builtin_memcpy(&bits, &val, 8);
    __builtin_nontemporal_store(bits,
        (unsigned long long*)(out + (size_t)point * 64 + sub));
}

extern "C" void kernel_launch(void* const* d_in, const int* in_sizes, int n_in,
                              void* d_out, int out_size, void* d_ws, size_t ws_size,
                              hipStream_t stream) {
    const float4* coords = (const float4*)d_in[0];
    const float4* refc   = (const float4*)d_in[1];
    const float2* t0 = (const float2*)d_in[2];
    const float2* t1 = (const float2*)d_in[3];
    const float2* t2 = (const float2*)d_in[4];
    const float2* t3 = (const float2*)d_in[5];
    float2* out = (float2*)d_out;
    int npts = in_sizes[0] / 4;

    size_t u_bytes     = (size_t)npts * 16;       // float4 per point
    size_t stage_bytes = (size_t)npts * 64 * 8;   // float2 per (slice,point)
    size_t needed = u_bytes + stage_bytes;

    if (d_ws != nullptr && ws_size >= needed) {
        float4* uws   = (float4*)d_ws;
        float2* stage = (float2*)((char*)d_ws + u_bytes);
        int chunks = (npts + 255) / 256;

        u_precompute_kernel<<<chunks, 256, 0, stream>>>(coords, refc, uws, npts);
        // 64 slices x chunks point-blocks; bid&7 -> XCD, phases sequential/XCD
        gather_kernel<<<64 * chunks, 256, 0, stream>>>(
            uws, t0, t1, t2, t3, stage, npts, chunks);
        transpose_kernel<<<(npts + 63) / 64, 256, 0, stream>>>(stage, out, npts);
    } else {
        int grid_x = (npts + 31) / 32;
        dim3 grid(grid_x, 8);
        energy4d_fallback<<<grid, 256, 0, stream>>>(coords, refc, t0, t1, t2, t3,
                                                    out, npts);
    }
}